// Round 5
// baseline (36.752 us; speedup 1.0000x reference)
//
#include <hip/hip_runtime.h>

typedef _Float16 half8 __attribute__((ext_vector_type(8)));
typedef float f32x16 __attribute__((ext_vector_type(16)));

#define NQ 4    // query groups (of 32) per wave
#define TS 4    // target slices (blocks) per (qt, bd)
#define GPW 16  // target groups per wave = 8192 / TS / 4 waves / 32

__device__ __forceinline__ float min3f(float a, float b, float c) {
    float d;
    asm("v_min3_f32 %0, %1, %2, %3" : "=v"(d) : "v"(a), "v"(b), "v"(c));
    return d;
}

// ---------------- prep: target A-fragment arrays for all 8 (dir,b) ----------------
// frag layout: half8 [8 bd][256 group][64 lane]. Lane l holds k-slots of target
// row (l&31). K-slot map (A/target), consistent with B below; MFMA dot product is
// K-permutation-invariant so any consistent map is correct:
//  half0: xh xh xl yh yh yl zh zh   half1: zl sqh sql 1 1 0 0 0
__global__ void cd_prep(const float* __restrict__ xyz1,
                        const float* __restrict__ xyz2,
                        _Float16* __restrict__ frag) {
    int tid  = blockIdx.x * 256 + threadIdx.x;   // 131072 threads
    int aidx = tid >> 14;                        // bd = dir*4+b
    int rem  = tid & 16383;
    int g = rem >> 6, l = rem & 63;
    int dir = aidx >> 2, b = aidx & 3;
    const float* src = (dir ? xyz1 : xyz2) + (size_t)b * 8192 * 3;
    int t = g * 32 + (l & 31);
    float x = src[t*3+0], y = src[t*3+1], z = src[t*3+2];
    float sq = __builtin_fmaf(x, x, __builtin_fmaf(y, y, z * z));
    _Float16 xh = (_Float16)x, yh = (_Float16)y, zh = (_Float16)z;
    _Float16 xl = (_Float16)(x - (float)xh);
    _Float16 yl = (_Float16)(y - (float)yh);
    _Float16 zl = (_Float16)(z - (float)zh);
    _Float16 sh = (_Float16)sq;
    _Float16 sl = (_Float16)(sq - (float)sh);
    const _Float16 one = (_Float16)1.0f, zero = (_Float16)0.0f;
    half8 f;
    if ((l >> 5) == 0) {
        f[0]=xh; f[1]=xh; f[2]=xl; f[3]=yh; f[4]=yh; f[5]=yl; f[6]=zh; f[7]=zh;
    } else {
        f[0]=zl; f[1]=sh; f[2]=sl; f[3]=one; f[4]=one; f[5]=zero; f[6]=zero; f[7]=zero;
    }
    ((half8*)frag)[(size_t)aidx * 16384 + g * 64 + l] = f;
}

// ---------------- main ----------------
// block: 4 waves, 128 shared queries, one 2048-target slice (512 targets/wave).
// D = |t|^2 + |q|^2 - 2 q.t computed entirely inside the MFMA (K-slot packing),
// so D >= ~0 and uint-bits atomicMin is valid.
#define FOLD(Dv, bj)                                   \
    bj = min3f(Dv[0],  Dv[1],  bj);                    \
    bj = min3f(Dv[2],  Dv[3],  bj);                    \
    bj = min3f(Dv[4],  Dv[5],  bj);                    \
    bj = min3f(Dv[6],  Dv[7],  bj);                    \
    bj = min3f(Dv[8],  Dv[9],  bj);                    \
    bj = min3f(Dv[10], Dv[11], bj);                    \
    bj = min3f(Dv[12], Dv[13], bj);                    \
    bj = min3f(Dv[14], Dv[15], bj);

__global__ void __launch_bounds__(256) cd_main(
        const float* __restrict__ xyz1, const float* __restrict__ xyz2,
        const _Float16* __restrict__ frag, unsigned int* __restrict__ out) {
    __shared__ float red[4][128];
    const int ts  = blockIdx.x;          // target slice (0..TS-1)
    const int qt  = blockIdx.y;          // query tile of 128 (0..63)
    const int bd  = blockIdx.z;          // dir*4 + b
    const int dir = bd >> 2, b = bd & 3;
    const int l = threadIdx.x & 63, w = threadIdx.x >> 6;
    const int h = l >> 5;
    const float* q = (dir ? xyz2 : xyz1) + (size_t)b * 8192 * 3;
    const int qbase = qt * 128;

    // B-fragments (queries). K-slot map (B/query), pairing A's slots:
    //  half0: mxh mxl mxh myh myl myh mzh mzl   half1: mzh 1 1 sqh sql 0 0 0
    half8 Bf[NQ];
    const _Float16 one = (_Float16)1.0f, zero = (_Float16)0.0f;
    #pragma unroll
    for (int j = 0; j < NQ; ++j) {
        int qi = qbase + j * 32 + (l & 31);
        float px = q[qi*3+0], py = q[qi*3+1], pz = q[qi*3+2];
        float mx = -2.f * px, my = -2.f * py, mz = -2.f * pz;
        float sq = __builtin_fmaf(px, px, __builtin_fmaf(py, py, pz * pz));
        _Float16 mxh = (_Float16)mx, mxl = (_Float16)(mx - (float)mxh);
        _Float16 myh = (_Float16)my, myl = (_Float16)(my - (float)myh);
        _Float16 mzh = (_Float16)mz, mzl = (_Float16)(mz - (float)mzh);
        _Float16 sh  = (_Float16)sq, sl  = (_Float16)(sq - (float)sh);
        half8 f;
        if (h == 0) { f[0]=mxh; f[1]=mxl; f[2]=mxh; f[3]=myh; f[4]=myl; f[5]=myh; f[6]=mzh; f[7]=mzl; }
        else        { f[0]=mzh; f[1]=one; f[2]=one; f[3]=sh; f[4]=sl; f[5]=zero; f[6]=zero; f[7]=zero; }
        Bf[j] = f;
    }

    f32x16 Z;
    #pragma unroll
    for (int i = 0; i < 16; ++i) Z[i] = 0.f;

    float best[NQ];
    #pragma unroll
    for (int j = 0; j < NQ; ++j) best[j] = 3.0e38f;

    // wave's target range: groups ts*64 + w*GPW .. +GPW, depth-2 reg prefetch.
    const half8* Ap = ((const half8*)frag) + (size_t)bd * 16384
                      + ((size_t)ts * 64 + (size_t)w * GPW) * 64 + l;

    half8 buf0 = Ap[0];
    half8 buf1 = Ap[64];
    #pragma unroll
    for (int g = 0; g < GPW; ++g) {
        half8 a = (g & 1) ? buf1 : buf0;
        if (g + 2 < GPW) {
            if (g & 1) buf1 = Ap[(size_t)(g + 2) * 64];
            else       buf0 = Ap[(size_t)(g + 2) * 64];
        }
        #pragma unroll
        for (int j = 0; j < NQ; ++j) {
            f32x16 D = __builtin_amdgcn_mfma_f32_32x32x16_f16(a, Bf[j], Z, 0, 0, 0);
            FOLD(D, best[j]);
        }
    }

    // C/D: col = lane&31; lane halves hold disjoint target rows of same cols.
    #pragma unroll
    for (int j = 0; j < NQ; ++j) {
        float o = __shfl_xor(best[j], 32, 64);
        best[j] = fminf(best[j], o);
    }
    if (l < 32) {
        #pragma unroll
        for (int j = 0; j < NQ; ++j) red[w][j * 32 + l] = best[j];
    }
    __syncthreads();
    if (threadIdx.x < 128) {
        int t = threadIdx.x;
        float m = fminf(fminf(red[0][t], red[1][t]), fminf(red[2][t], red[3][t]));
        atomicMin(out + (size_t)dir * 32768 + (size_t)b * 8192 + qbase + t,
                  __float_as_uint(m));
    }
}

extern "C" void kernel_launch(void* const* d_in, const int* in_sizes, int n_in,
                              void* d_out, int out_size, void* d_ws, size_t ws_size,
                              hipStream_t stream) {
    const float* xyz1 = (const float*)d_in[0];
    const float* xyz2 = (const float*)d_in[1];
    _Float16* frag = (_Float16*)d_ws;   // 2 MB of scratch

    // 0x7F7F7F7F == 3.39e38f upper bound for bits-atomicMin (graph-capture-safe).
    hipMemsetAsync(d_out, 0x7F, (size_t)out_size * sizeof(float), stream);

    cd_prep<<<512, 256, 0, stream>>>(xyz1, xyz2, frag);

    dim3 grid(TS, 64, 8);   // target slices x query tiles x (dir*4+b)
    cd_main<<<grid, 256, 0, stream>>>(xyz1, xyz2, frag, (unsigned int*)d_out);
}